// Round 12
// baseline (182.233 us; speedup 1.0000x reference)
//
#include <hip/hip_runtime.h>
#include <cmath>

// x,y: (16,3,512,512) f32. Fused separable-Gaussian SSIM, scalar mean output.
// Wave-independent design: one wave64 owns one full image row (8 cols/lane).
// v-conv streams 11 input rows through registers; h-conv halos come from
// neighbor LANES via __shfl (no LDS tile, no __syncthreads anywhere).
// Reduction: wave shuffle tree -> 64-slot scattered double atomics.
constexpr int IMG_H = 512;
constexpr int IMG_W = 512;
constexpr int PLANES = 48;
constexpr int NSLOT = 64;                 // accumulator slots (64B apart)
constexpr long long TOTAL_PIX = (long long)PLANES * IMG_H * IMG_W;

struct GWin { float g[11]; };

template<bool CHK>
__device__ __forceinline__ void ld8(const float* __restrict__ base, int gr, int c0,
                                    float (&v)[8]) {
    if (CHK && (unsigned)gr >= (unsigned)IMG_H) {
#pragma unroll
        for (int t = 0; t < 8; ++t) v[t] = 0.f;
        return;
    }
    const float4 lo = *(const float4*)(base + (size_t)gr * IMG_W + c0);
    const float4 hi = *(const float4*)(base + (size_t)gr * IMG_W + c0 + 4);
    v[0] = lo.x; v[1] = lo.y; v[2] = lo.z; v[3] = lo.w;
    v[4] = hi.x; v[5] = hi.y; v[6] = hi.z; v[7] = hi.w;
}

template<bool CHK>
__device__ __forceinline__ float row_body(const float* __restrict__ xp,
                                          const float* __restrict__ yp,
                                          int r, int l, const GWin& win)
{
    const int c0 = 8 * l;

    // ---- vertical 11-tap conv of {x,y,xx,yy,xy} for row r, 8 cols ----
    float a[5][8];
#pragma unroll
    for (int f = 0; f < 5; ++f)
#pragma unroll
        for (int t = 0; t < 8; ++t) a[f][t] = 0.f;

#pragma unroll
    for (int i = 0; i < 11; ++i) {
        float xv[8], yv[8];
        ld8<CHK>(xp, r - 5 + i, c0, xv);
        ld8<CHK>(yp, r - 5 + i, c0, yv);
        const float g = win.g[i];
#pragma unroll
        for (int t = 0; t < 8; ++t) {
            a[0][t] += g * xv[t];
            a[1][t] += g * yv[t];
            a[2][t] += g * (xv[t] * xv[t]);
            a[3][t] += g * (yv[t] * yv[t]);
            a[4][t] += g * (xv[t] * yv[t]);
        }
    }

    // ---- horizontal 11-tap conv; halos via lane shuffles (zero-pad edges) ----
    float m[5][8];
#pragma unroll
    for (int f = 0; f < 5; ++f) {
        float w18[18];
#pragma unroll
        for (int t = 0; t < 5; ++t) {                 // cols 8l-5..8l-1
            const float v = __shfl_up(a[f][3 + t], 1);
            w18[t] = (l == 0) ? 0.f : v;
        }
#pragma unroll
        for (int t = 0; t < 8; ++t) w18[5 + t] = a[f][t];
#pragma unroll
        for (int t = 0; t < 5; ++t) {                 // cols 8l+8..8l+12
            const float v = __shfl_down(a[f][t], 1);
            w18[13 + t] = (l == 63) ? 0.f : v;
        }
        // output col 8l+u: window cols 8l+u-5..8l+u+5 -> w18[u..u+10]
#pragma unroll
        for (int u = 0; u < 8; ++u) {
            float s = 0.f;
#pragma unroll
            for (int k = 0; k < 11; ++k) s += win.g[k] * w18[u + k];
            m[f][u] = s;
        }
    }

    // ---- SSIM map for 8 pixels ----
    float ls = 0.f;
#pragma unroll
    for (int u = 0; u < 8; ++u) {
        const float mx  = m[0][u], my  = m[1][u];
        const float mxx = m[2][u], myy = m[3][u], mxy = m[4][u];
        const float mu_x_sq = mx * mx;
        const float mu_y_sq = my * my;
        const float mu_xy   = mx * my;
        const float sig_x  = mxx - mu_x_sq;
        const float sig_y  = myy - mu_y_sq;
        const float sig_xy = mxy - mu_xy;
        const float C1 = 0.01f * 0.01f;
        const float C2 = 0.03f * 0.03f;
        const float n = (2.f * mu_xy + C1) * (2.f * sig_xy + C2);
        const float d = (mu_x_sq + mu_y_sq + C1) * (sig_x + sig_y + C2);
        ls += n * __builtin_amdgcn_rcpf(d + 1e-8f);   // ~1 ulp; mean-safe
    }
    return ls;
}

__global__ __launch_bounds__(256)
void ssim_wave_kernel(const float* __restrict__ x,
                      const float* __restrict__ y,
                      double* __restrict__ accum,
                      GWin win)
{
    const int tid = threadIdx.x;
    const int l   = tid & 63;
    const int wid = (blockIdx.x * 256 + tid) >> 6;    // global wave id
    const int row   = wid & (IMG_H - 1);
    const int plane = wid >> 9;

    const float* __restrict__ xp = x + (size_t)plane * (IMG_H * IMG_W);
    const float* __restrict__ yp = y + (size_t)plane * (IMG_H * IMG_W);

    float lsum;
    if (row >= 5 && row < IMG_H - 5)
        lsum = row_body<false>(xp, yp, row, l, win);
    else
        lsum = row_body<true>(xp, yp, row, l, win);

    // wave reduction, then one scattered atomic per wave
#pragma unroll
    for (int off = 32; off; off >>= 1) lsum += __shfl_down(lsum, off);
    if (l == 0)
        atomicAdd(&accum[(wid & (NSLOT - 1)) * 8], (double)lsum);  // 64B stride
}

__global__ void ssim_finalize_kernel(const double* __restrict__ accum,
                                     float* __restrict__ out)
{
    double s = 0.0;
    for (int i = 0; i < NSLOT; ++i) s += accum[i * 8];
    out[0] = (float)(s / (double)TOTAL_PIX);
}

extern "C" void kernel_launch(void* const* d_in, const int* in_sizes, int n_in,
                              void* d_out, int out_size, void* d_ws, size_t ws_size,
                              hipStream_t stream) {
    const float* x = (const float*)d_in[0];
    const float* y = (const float*)d_in[1];
    float* out = (float*)d_out;
    double* accum = (double*)d_ws;

    GWin win;
    {
        double g[11], s = 0.0;
        for (int i = 0; i < 11; ++i) {
            double d = (double)i - 5.0;
            g[i] = std::exp(-(d * d) / (2.0 * 1.5 * 1.5));
            s += g[i];
        }
        for (int i = 0; i < 11; ++i) win.g[i] = (float)(g[i] / s);
    }

    hipMemsetAsync(d_ws, 0, NSLOT * 8 * sizeof(double), stream);

    // 48 planes x 512 rows = 24576 waves = 6144 blocks of 256 (4 indep waves)
    const int nblocks = PLANES * IMG_H / 4;
    ssim_wave_kernel<<<nblocks, 256, 0, stream>>>(x, y, accum, win);
    ssim_finalize_kernel<<<1, 1, 0, stream>>>(accum, out);
}

// Round 13
// 102.533 us; speedup vs baseline: 1.7773x; 1.7773x over previous
//
#include <hip/hip_runtime.h>
#include <cmath>

// x,y: (16,3,512,512) f32. Fused separable-Gaussian SSIM, scalar mean output.
// 2-row rounds for occupancy: v-conv (2 cols/lane, fresh 12-row loads) ->
// 21KB bank-swizzled LDS handoff -> h-conv (8 cols/lane, waves 0-1) -> SSIM.
// 7 blocks/CU by LDS; fresh loads keep VGPR ~90 (rings/prefetch proved fatal).
constexpr int IMG_H = 512;
constexpr int IMG_W = 512;
constexpr int PLANES = 48;
constexpr int R_OUT = 8;                 // output rows per block (4 rounds of 2)
constexpr int BANDS = IMG_H / R_OUT;     // 64
constexpr int PSTR = 528;                // field-row dwords; col c at p = c+8
constexpr long long TOTAL_PIX = (long long)PLANES * IMG_H * IMG_W;

struct GWin { float g[11]; };

// XOR bank swizzle on within-field-row dword offset (bits 2..4 ^= bits 5..7).
// float2 writes at even p and float4 reads at 4-aligned p stay contiguous.
__device__ __forceinline__ int swzd(int p) { return p ^ (((p >> 5) & 7) << 2); }

template<bool CHK>
__device__ __forceinline__ float2 ld2(const float* __restrict__ base, int gr, int c0) {
    if (CHK && (unsigned)gr >= (unsigned)IMG_H) return make_float2(0.f, 0.f);
    return *(const float2*)(base + (size_t)gr * IMG_W + c0);
}

// horizontal 11-tap conv + SSIM over one LDS row (5 fields), 8 cols per lane
__device__ __forceinline__ float hpass8(const float (* __restrict__ fr)[PSTR],
                                        int l, const GWin& win) {
    int pb[6];
#pragma unroll
    for (int B = 0; B < 6; ++B) {
        const int blk = 2 * l + B;
        pb[B] = blk ^ ((blk >> 3) & 7);
    }
    float m[5][8];
#pragma unroll
    for (int f = 0; f < 5; ++f) {
        float w24[24];
#pragma unroll
        for (int B = 0; B < 6; ++B) {
            const float4 v = *(const float4*)&fr[f][4 * pb[B]];
            w24[4 * B + 0] = v.x;  w24[4 * B + 1] = v.y;
            w24[4 * B + 2] = v.z;  w24[4 * B + 3] = v.w;
        }
        // output col c = 8l+j; window floats p = c+3..c+13 -> w24[j+3+k]
#pragma unroll
        for (int j = 0; j < 8; ++j) {
            float s = 0.f;
#pragma unroll
            for (int k = 0; k < 11; ++k) s += win.g[k] * w24[j + 3 + k];
            m[f][j] = s;
        }
    }
    float ls = 0.f;
#pragma unroll
    for (int u = 0; u < 8; ++u) {
        const float mx  = m[0][u], my  = m[1][u];
        const float mxx = m[2][u], myy = m[3][u], mxy = m[4][u];
        const float mu_x_sq = mx * mx;
        const float mu_y_sq = my * my;
        const float mu_xy   = mx * my;
        const float sig_x  = mxx - mu_x_sq;
        const float sig_y  = myy - mu_y_sq;
        const float sig_xy = mxy - mu_xy;
        const float C1 = 0.01f * 0.01f;
        const float C2 = 0.03f * 0.03f;
        const float n = (2.f * mu_xy + C1) * (2.f * sig_xy + C2);
        const float d = (mu_x_sq + mu_y_sq + C1) * (sig_x + sig_y + C2);
        ls += n * __builtin_amdgcn_rcpf(d + 1e-8f);   // ~1 ulp; mean-safe
    }
    return ls;
}

template<bool CHK>
__device__ __forceinline__ float rounds_body(const float* __restrict__ xp,
                                             const float* __restrict__ yp,
                                             int r0, int c0, int tid,
                                             float (&hbuf)[2][5][PSTR],
                                             const GWin& win)
{
    const int pws = swzd(2 * tid + 8);   // v-write physical offset (pair-contiguous)
    float lsum = 0.f;

#pragma unroll 1
    for (int rr = 0; rr < 4; ++rr) {
        const int rbase = r0 + 2 * rr;

        // ---- vertical 11-tap conv of {x,y,xx,yy,xy} for rows rbase, rbase+1 ----
        // fresh 12-row loads (short lifetimes -> low VGPR), products recomputed
        float2 acc[2][5];
#pragma unroll
        for (int j = 0; j < 2; ++j)
#pragma unroll
            for (int f = 0; f < 5; ++f) acc[j][f] = make_float2(0.f, 0.f);

#pragma unroll
        for (int i = 0; i < 12; ++i) {
            const float2 xv = ld2<CHK>(xp, rbase - 5 + i, c0);
            const float2 yv = ld2<CHK>(yp, rbase - 5 + i, c0);
            const float2 pxx = make_float2(xv.x * xv.x, xv.y * xv.y);
            const float2 pyy = make_float2(yv.x * yv.x, yv.y * yv.y);
            const float2 pxy = make_float2(xv.x * yv.x, xv.y * yv.y);
            if (i < 11) {                         // row rbase, tap t = i
                const float g = win.g[i];
                acc[0][0].x += g * xv.x;   acc[0][0].y += g * xv.y;
                acc[0][1].x += g * yv.x;   acc[0][1].y += g * yv.y;
                acc[0][2].x += g * pxx.x;  acc[0][2].y += g * pxx.y;
                acc[0][3].x += g * pyy.x;  acc[0][3].y += g * pyy.y;
                acc[0][4].x += g * pxy.x;  acc[0][4].y += g * pxy.y;
            }
            if (i > 0) {                          // row rbase+1, tap t = i-1
                const float g = win.g[i - 1];
                acc[1][0].x += g * xv.x;   acc[1][0].y += g * xv.y;
                acc[1][1].x += g * yv.x;   acc[1][1].y += g * yv.y;
                acc[1][2].x += g * pxx.x;  acc[1][2].y += g * pxx.y;
                acc[1][3].x += g * pyy.x;  acc[1][3].y += g * pyy.y;
                acc[1][4].x += g * pxy.x;  acc[1][4].y += g * pxy.y;
            }
        }

#pragma unroll
        for (int j = 0; j < 2; ++j)
#pragma unroll
            for (int f = 0; f < 5; ++f)
                *(float2*)&hbuf[j][f][pws] = acc[j][f];

        __syncthreads();

        // ---- horizontal conv + SSIM: waves 0,1 only (row = tid>>6) ----
        if (tid < 128)
            lsum += hpass8(hbuf[tid >> 6], tid & 63, win);

        __syncthreads();   // protect hbuf before next round's writes
    }
    return lsum;
}

__global__ __launch_bounds__(256)
void ssim_r2_kernel(const float* __restrict__ x,
                    const float* __restrict__ y,
                    double* __restrict__ accum,
                    GWin win)
{
    __shared__ __align__(16) float hbuf[2][5][PSTR];   // 21.12 KB
    __shared__ float wsum[4];

    const int tid   = threadIdx.x;
    const int band  = blockIdx.x & (BANDS - 1);
    const int plane = blockIdx.x >> 6;
    const int r0    = band * R_OUT;
    const int c0    = tid * 2;

    const float* __restrict__ xp = x + (size_t)plane * (IMG_H * IMG_W);
    const float* __restrict__ yp = y + (size_t)plane * (IMG_H * IMG_W);

    // zero halo cols once: p in [0,8) and [520,528), 2 rows x 5 fields
    if (tid < 160) {
        int rf = tid >> 4, w = tid & 15;
        int p  = (w < 8) ? w : (512 + w);       // 0..7, 520..527
        (&hbuf[0][0][0])[rf * PSTR + swzd(p)] = 0.f;
    }
    // (ordered before first h-read by the first in-round __syncthreads)

    float lsum;
    if (band >= 1 && band <= BANDS - 2)
        lsum = rounds_body<false>(xp, yp, r0, c0, tid, hbuf, win);
    else
        lsum = rounds_body<true>(xp, yp, r0, c0, tid, hbuf, win);

    // block reduction
#pragma unroll
    for (int off = 32; off; off >>= 1) lsum += __shfl_down(lsum, off);
    if ((tid & 63) == 0) wsum[tid >> 6] = lsum;
    __syncthreads();
    if (tid == 0)
        atomicAdd(accum, (double)(wsum[0] + wsum[1] + wsum[2] + wsum[3]));
}

__global__ void ssim_finalize_kernel(const double* __restrict__ accum,
                                     float* __restrict__ out)
{
    out[0] = (float)(accum[0] / (double)TOTAL_PIX);
}

extern "C" void kernel_launch(void* const* d_in, const int* in_sizes, int n_in,
                              void* d_out, int out_size, void* d_ws, size_t ws_size,
                              hipStream_t stream) {
    const float* x = (const float*)d_in[0];
    const float* y = (const float*)d_in[1];
    float* out = (float*)d_out;
    double* accum = (double*)d_ws;

    GWin win;
    {
        double g[11], s = 0.0;
        for (int i = 0; i < 11; ++i) {
            double d = (double)i - 5.0;
            g[i] = std::exp(-(d * d) / (2.0 * 1.5 * 1.5));
            s += g[i];
        }
        for (int i = 0; i < 11; ++i) win.g[i] = (float)(g[i] / s);
    }

    hipMemsetAsync(d_ws, 0, sizeof(double), stream);

    const int nblocks = PLANES * BANDS;  // 3072
    ssim_r2_kernel<<<nblocks, 256, 0, stream>>>(x, y, accum, win);
    ssim_finalize_kernel<<<1, 1, 0, stream>>>(accum, out);
}

// Round 15
// 77.860 us; speedup vs baseline: 2.3405x; 1.3169x over previous
//
#include <hip/hip_runtime.h>
#include <cmath>

// x,y: (16,3,512,512) f32. Fused separable-Gaussian SSIM, scalar mean output.
// R9 quad structure with LDS shrunk to exactly 40 KB (4 blocks/CU):
//   per 4 output rows: stream 14 input rows (2 cols/lane), v-conv 5 fields ->
//   bank-swizzled 512-dword LDS rows (no halo slots) -> h-conv 8 cols/lane
//   with register edge masking -> SSIM. 2 quads/block, 4 barriers total.
// Reduction: wave shuffle -> scattered global double atomics (no LDS scratch).
constexpr int IMG_H = 512;
constexpr int IMG_W = 512;
constexpr int PLANES = 48;
constexpr int R_OUT = 8;                 // output rows per block (2 quads)
constexpr int BANDS = IMG_H / R_OUT;     // 64
constexpr int PSTR = 512;                // field-row dwords; col c at dword c
constexpr int NSLOT = 64;                // global accumulator slots (64B apart)
constexpr long long TOTAL_PIX = (long long)PLANES * IMG_H * IMG_W;

struct GWin { float g[11]; };

// XOR bank swizzle on within-field-row dword offset (bits 2..4 ^= bits 5..7).
// Fully periodic over 512 dwords; b64 pairs (even base) and b128 quads
// (4-aligned base) stay contiguous (only bits >=2 are modified).
__device__ __forceinline__ int swzd(int d) { return d ^ (((d >> 5) & 7) << 2); }
// Block-of-4-dwords level XOR: swzd(4b) == 4*swzd4(b).
__device__ __forceinline__ int swzd4(int b) { return b ^ ((b >> 3) & 7); }

template<bool CHK>
__device__ __forceinline__ float2 ld2(const float* __restrict__ base, int gr, int c0) {
    if (CHK && (unsigned)gr >= (unsigned)IMG_H) return make_float2(0.f, 0.f);
    return *(const float2*)(base + (size_t)gr * IMG_W + c0);
}

// horizontal 11-tap conv + SSIM over one LDS row (5 fields), 8 cols per lane.
// Window w24 covers cols 8l-8..8l+15 (blocks 2l-2..2l+3, clamped); lanes 0/63
// zero their out-of-image taps in registers.
__device__ __forceinline__ float hpass8(const float* __restrict__ fr0,
                                        int l, const GWin& win) {
    int pb[6];
#pragma unroll
    for (int B = 0; B < 6; ++B) {
        int blk = 2 * l - 2 + B;
        blk = blk < 0 ? 0 : (blk > 127 ? 127 : blk);
        pb[B] = 4 * swzd4(blk);
    }
    float m[5][8];
#pragma unroll
    for (int f = 0; f < 5; ++f) {
        const float* fr = fr0 + f * PSTR;
        float w24[24];
#pragma unroll
        for (int B = 0; B < 6; ++B) {
            const float4 v = *(const float4*)&fr[pb[B]];
            w24[4 * B + 0] = v.x;  w24[4 * B + 1] = v.y;
            w24[4 * B + 2] = v.z;  w24[4 * B + 3] = v.w;
        }
        if (l == 0)  { w24[3] = w24[4] = w24[5] = w24[6] = w24[7] = 0.f; }
        if (l == 63) { w24[16] = w24[17] = w24[18] = w24[19] = w24[20] = 0.f; }
        // output col c = 8l+j: window cols c-5..c+5 -> w24[j+3+k], k=0..10
#pragma unroll
        for (int j = 0; j < 8; ++j) {
            float s = 0.f;
#pragma unroll
            for (int k = 0; k < 11; ++k) s += win.g[k] * w24[j + 3 + k];
            m[f][j] = s;
        }
    }
    float ls = 0.f;
#pragma unroll
    for (int u = 0; u < 8; ++u) {
        const float mx  = m[0][u], my  = m[1][u];
        const float mxx = m[2][u], myy = m[3][u], mxy = m[4][u];
        const float mu_x_sq = mx * mx;
        const float mu_y_sq = my * my;
        const float mu_xy   = mx * my;
        const float sig_x  = mxx - mu_x_sq;
        const float sig_y  = myy - mu_y_sq;
        const float sig_xy = mxy - mu_xy;
        const float C1 = 0.01f * 0.01f;
        const float C2 = 0.03f * 0.03f;
        const float n = (2.f * mu_xy + C1) * (2.f * sig_xy + C2);
        const float d = (mu_x_sq + mu_y_sq + C1) * (sig_x + sig_y + C2);
        ls += n * __builtin_amdgcn_rcpf(d + 1e-8f);   // ~1 ulp; mean-safe
    }
    return ls;
}

template<bool CHK>
__device__ __forceinline__ float quad_rounds(const float* __restrict__ xp,
                                             const float* __restrict__ yp,
                                             int r0, int c0, int tid,
                                             float* __restrict__ hb,   // [4][5][PSTR]
                                             const GWin& win)
{
    const int pws = swzd(2 * tid);       // v-write physical dword (b64-contiguous)
    const int row = tid >> 6, l = tid & 63;
    float lsum = 0.f;

#pragma unroll 1
    for (int q = 0; q < 2; ++q) {
        const int rq = r0 + 4 * q;

        // ---- vertical 11-tap conv of {x,y,xx,yy,xy} for 4 rows, streaming ----
        float2 acc[4][5];
#pragma unroll
        for (int j = 0; j < 4; ++j)
#pragma unroll
            for (int f = 0; f < 5; ++f) acc[j][f] = make_float2(0.f, 0.f);

#pragma unroll
        for (int k = 0; k < 14; ++k) {
            const float2 xv = ld2<CHK>(xp, rq - 5 + k, c0);
            const float2 yv = ld2<CHK>(yp, rq - 5 + k, c0);
            const float2 pxx = make_float2(xv.x * xv.x, xv.y * xv.y);
            const float2 pyy = make_float2(yv.x * yv.x, yv.y * yv.y);
            const float2 pxy = make_float2(xv.x * yv.x, xv.y * yv.y);
#pragma unroll
            for (int j = 0; j < 4; ++j) {
                const int t = k - j;               // compile-time
                if (t >= 0 && t <= 10) {
                    const float g = win.g[t];
                    acc[j][0].x += g * xv.x;   acc[j][0].y += g * xv.y;
                    acc[j][1].x += g * yv.x;   acc[j][1].y += g * yv.y;
                    acc[j][2].x += g * pxx.x;  acc[j][2].y += g * pxx.y;
                    acc[j][3].x += g * pyy.x;  acc[j][3].y += g * pyy.y;
                    acc[j][4].x += g * pxy.x;  acc[j][4].y += g * pxy.y;
                }
            }
        }

#pragma unroll
        for (int j = 0; j < 4; ++j)
#pragma unroll
            for (int f = 0; f < 5; ++f)
                *(float2*)&hb[(j * 5 + f) * PSTR + pws] = acc[j][f];

        __syncthreads();

        lsum += hpass8(hb + row * 5 * PSTR, l, win);

        __syncthreads();   // protect hbuf before next quad's writes
    }
    return lsum;
}

__global__ __launch_bounds__(256)
void ssim_q512_kernel(const float* __restrict__ x,
                      const float* __restrict__ y,
                      double* __restrict__ accum,
                      GWin win)
{
    __shared__ __align__(16) float hbuf[4 * 5 * PSTR];   // exactly 40960 B

    const int tid   = threadIdx.x;
    const int band  = blockIdx.x & (BANDS - 1);
    const int plane = blockIdx.x >> 6;
    const int r0    = band * R_OUT;
    const int c0    = tid * 2;

    const float* __restrict__ xp = x + (size_t)plane * (IMG_H * IMG_W);
    const float* __restrict__ yp = y + (size_t)plane * (IMG_H * IMG_W);

    float lsum;
    if (band >= 1 && band <= BANDS - 2)
        lsum = quad_rounds<false>(xp, yp, r0, c0, tid, hbuf, win);
    else
        lsum = quad_rounds<true>(xp, yp, r0, c0, tid, hbuf, win);

    // wave reduction, then one scattered global atomic per wave (no LDS)
#pragma unroll
    for (int off = 32; off; off >>= 1) lsum += __shfl_down(lsum, off);
    if ((tid & 63) == 0) {
        const int wid = blockIdx.x * 4 + (tid >> 6);
        atomicAdd(&accum[(wid & (NSLOT - 1)) * 8], (double)lsum);  // 64B stride
    }
}

__global__ void ssim_finalize_kernel(const double* __restrict__ accum,
                                     float* __restrict__ out)
{
    double s = 0.0;
    for (int i = 0; i < NSLOT; ++i) s += accum[i * 8];
    out[0] = (float)(s / (double)TOTAL_PIX);
}

extern "C" void kernel_launch(void* const* d_in, const int* in_sizes, int n_in,
                              void* d_out, int out_size, void* d_ws, size_t ws_size,
                              hipStream_t stream) {
    const float* x = (const float*)d_in[0];
    const float* y = (const float*)d_in[1];
    float* out = (float*)d_out;
    double* accum = (double*)d_ws;

    GWin win;
    {
        double g[11], s = 0.0;
        for (int i = 0; i < 11; ++i) {
            double d = (double)i - 5.0;
            g[i] = std::exp(-(d * d) / (2.0 * 1.5 * 1.5));
            s += g[i];
        }
        for (int i = 0; i < 11; ++i) win.g[i] = (float)(g[i] / s);
    }

    (void)hipMemsetAsync(d_ws, 0, NSLOT * 8 * sizeof(double), stream);

    const int nblocks = PLANES * BANDS;  // 3072
    ssim_q512_kernel<<<nblocks, 256, 0, stream>>>(x, y, accum, win);
    ssim_finalize_kernel<<<1, 1, 0, stream>>>(accum, out);
}